// Round 5
// baseline (8597826.562 us; speedup 1.0000x reference)
//
#include <hip/hip_runtime.h>

// BiLSTM-CRF, f32-faithful.
// Gate-split cooperative recurrence (4 blocks/chain, each owns ONE gate's
// Whh rows = 256KB = 64 f32/thread in VGPRs), complete-gate exchange,
// redundant h/c update in every block. Sync: same-XCD L2 fast path
// (plain stores + sc0 loads) selected by per-launch XCC_ID+probe handshake;
// agent-atomic fallback otherwise.
//
// R5 fix: R4 deadlocked-to-bailout every step (209ms dispatches, VALUBusy 1%)
// because flag-store and flag-poll lived in one wave under if/else — the wave
// could execute the poll branch to bailout before the store. Store moved to
// wave 1 (t==64); polls stay in wave 0 (t<3). Independent wave scheduling
// makes the store unblockable -> no deadlock by construction.

#define SLEN 512
#define NTAG 9
#define NEGV -10000.0f

typedef float f32x2 __attribute__((ext_vector_type(2)));
typedef float f32x4 __attribute__((ext_vector_type(4)));

__device__ __forceinline__ float qsum(float v){
  int t = __builtin_amdgcn_update_dpp(0, __float_as_int(v), 0xB1, 0xF, 0xF, false); // [1,0,3,2]
  v += __int_as_float(t);
  t = __builtin_amdgcn_update_dpp(0, __float_as_int(v), 0x4E, 0xF, 0xF, false);     // [2,3,0,1]
  return v + __int_as_float(t);
}

// sc0 (L1-bypass, L2-hit) loads for same-XCD polling/data
__device__ __forceinline__ int ld_sc0_i(const int* p){
  int v;
  asm volatile("global_load_dword %0, %1, off sc0\n\ts_waitcnt vmcnt(0)"
               : "=v"(v) : "v"(p) : "memory");
  return v;
}
__device__ __forceinline__ void ld4_sc0(const float* p0, const float* p1,
                                        const float* p2, const float* p3,
                                        float &a, float &b, float &c, float &d){
  asm volatile("global_load_dword %0, %4, off sc0\n\t"
               "global_load_dword %1, %5, off sc0\n\t"
               "global_load_dword %2, %6, off sc0\n\t"
               "global_load_dword %3, %7, off sc0\n\t"
               "s_waitcnt vmcnt(0)"
               : "=&v"(a), "=&v"(b), "=&v"(c), "=&v"(d)
               : "v"(p0), "v"(p1), "v"(p2), "v"(p3) : "memory");
}

// dual-batch gemv over this thread's 64-k slice. LDS layout: quarter c at
// base = c*132 floats (pad 4 breaks the 512B bank-aliased stride), pairs
// (k,b) interleaved: pos = (k&63)*2 + b. w[p] = cols {2p, 2p+1}.
__device__ __forceinline__ f32x2 gemv64(const f32x2 (&w)[32], const float* base){
  f32x2 s = {0.f, 0.f};
  #pragma unroll
  for (int p=0; p<32; p++){
    f32x4 hv = *(const f32x4*)(base + p*4);
    f32x2 h01 = {hv.x, hv.y}, h23 = {hv.z, hv.w};
    asm("v_pk_fma_f32 %0, %1, %2, %0 op_sel:[0,0,0] op_sel_hi:[0,1,1]"
        : "+v"(s) : "v"(w[p]), "v"(h01));
    asm("v_pk_fma_f32 %0, %1, %2, %0 op_sel:[1,0,0] op_sel_hi:[1,1,1]"
        : "+v"(s) : "v"(w[p]), "v"(h23));
  }
  return s;
}

// wS[(((m*2+d)*4+g)*16 + inst)*4096 + t*4 + e] = W[g*256 + (t>>2)][(t&3)*64 + inst*4 + e]
__global__ void prep_k(const float* __restrict__ wihf, const float* __restrict__ whhf,
                       const float* __restrict__ wihr, const float* __restrict__ whhr,
                       float* __restrict__ wS){
  for (int i = blockIdx.x*blockDim.x + threadIdx.x; i < (1<<20); i += gridDim.x*blockDim.x){
    int e = i&3, tt = (i>>2)&1023, inst = (i>>12)&15, g = (i>>16)&3, dd = (i>>18)&1, m = (i>>19)&1;
    int row = g*256 + (tt>>2);
    int col = (tt&3)*64 + inst*4 + e;
    const float* s = m ? (dd? whhr : whhf) : (dd? wihr : wihf);
    wS[i] = s[row*256 + col];
  }
}

// xproj: block (d, g, bp) computes gate-g pre-activations (incl. bias) for
// batches {2bp, 2bp+1}, all Sc steps of chunk c0. Double-buffered LDS x.
__global__ __launch_bounds__(1024, 4) void xproj_k(
    int c0, int Sc,
    const int* __restrict__ ids, const float* __restrict__ embed,
    const float* __restrict__ wS,
    const float* __restrict__ bias_f, const float* __restrict__ bias_r,
    float* __restrict__ xg, long xg_par_str)
{
  __shared__ __align__(16) float xl2[2][544];
  __shared__ int ids_l[1024];
  const int t = threadIdx.x;
  const int bid = blockIdx.x;
  const int bp = bid & 31, g = (bid>>5)&3, d = bid>>7;
  const int j = t>>2, c = t&3;

  f32x2 w[32];
  {
    const f32x4* wp = (const f32x4*)(wS + (long)((d*4+g)*16)*4096);
    #pragma unroll
    for (int inst=0; inst<16; inst++){
      f32x4 v = wp[inst*1024 + t];
      w[inst*2]   = f32x2{v.x, v.y};
      w[inst*2+1] = f32x2{v.z, v.w};
    }
  }
  const float bb = (d ? bias_r : bias_f)[g*256 + j];
  for (int i=t; i<2*Sc; i+=1024){
    int b = (i>=Sc) ? 1 : 0, sp = i - b*Sc;
    int sg = d ? (SLEN-1-(c0*Sc+sp)) : (c0*Sc+sp);
    ids_l[i] = ids[(bp*2+b)*SLEN + sg];
  }
  __syncthreads();
  const int bl = t&1, kk = t>>1;          // loader mapping (t<128)
  if (t < 128){
    f32x4 v = ((const f32x4*)embed)[(long)ids_l[bl*Sc]*64 + kk];
    #pragma unroll
    for (int ii=0; ii<4; ii++){
      int k = kk*4+ii;
      xl2[0][(k>>6)*132 + (k&63)*2 + bl] = v[ii];
    }
  }
  __syncthreads();
  float* xgb = xg + (long)(c0&1)*xg_par_str;
  for (int sp=0; sp<Sc; sp++){
    f32x4 pfv;
    const bool hpf = (sp+1 < Sc) && (t < 128);
    if (hpf) pfv = ((const f32x4*)embed)[(long)ids_l[bl*Sc + sp+1]*64 + kk];
    f32x2 s = gemv64(w, &xl2[sp&1][c*132]);
    s.x = qsum(s.x); s.y = qsum(s.y);
    if (c < 2){
      float val = (c ? s.y : s.x) + bb;
      xgb[((long)(d*Sc+sp)*64 + (bp*2+c))*1024 + g*256 + j] = val;
    }
    if (hpf){
      #pragma unroll
      for (int ii=0; ii<4; ii++){
        int k = kk*4+ii;
        xl2[(sp+1)&1][(k>>6)*132 + (k&63)*2 + bl] = pfv[ii];
      }
    }
    __syncthreads();
  }
}

// recur: blockIdx bits [2:0]=grp_lo, [4:3]=g, [7:5]=grp_hi -> group members
// agree on XCD under both %8-round-robin and 32-slab mappings.
__global__ __launch_bounds__(1024, 4) void recur_k(
    int c0, int Sc,
    const int* __restrict__ ids,
    const float* __restrict__ wS,
    const float* __restrict__ xg, long xg_par_str,
    float* __restrict__ hs,
    float* __restrict__ st_h, float* __restrict__ st_c,
    float* __restrict__ send, int* __restrict__ flags,
    int* __restrict__ hsk1, int* __restrict__ hsk2, int* __restrict__ probe)
{
  __shared__ __align__(16) float hl2[544];
  __shared__ int ml[1024];
  __shared__ int fast_sh;
  const int t = threadIdx.x;
  const int bid = blockIdx.x;
  const int g = (bid>>3)&3;
  const int grp = (bid&7) | ((bid>>5)<<3);
  const int d = grp>>5, bp = grp&31;
  const int j = t>>2, c = t&3;

  f32x2 w[32];
  {
    const f32x4* wp = (const f32x4*)(wS + (long)((8 + d*4+g)*16)*4096);
    #pragma unroll
    for (int inst=0; inst<16; inst++){
      f32x4 v = wp[inst*1024 + t];
      w[inst*2]   = f32x2{v.x, v.y};
      w[inst*2+1] = f32x2{v.z, v.w};
    }
  }
  for (int i=t; i<2*Sc; i+=1024){
    int b = (i>=Sc) ? 1 : 0, sp = i - b*Sc;
    int sg = d ? (SLEN-1-(c0*Sc+sp)) : (c0*Sc+sp);
    ml[i] = ids[(bp*2+b)*SLEN + sg];
  }
  // ---- handshake: choose fast (same-XCD L2) vs fallback (agent atomics) ----
  if (t == 0){
    int xcc = __builtin_amdgcn_s_getreg(6164);   // HW_REG_XCC_ID(20), off 0, size 4
    int tag = (c0+1) << 8;
    probe[grp*4+g] = tag;
    asm volatile("s_waitcnt vmcnt(0)" ::: "memory");
    __hip_atomic_store(&hsk1[grp*4+g], tag | (xcc&15), __ATOMIC_RELEASE, __HIP_MEMORY_SCOPE_AGENT);
    int fast = 1;
    for (int s3=1; s3<4; s3++){
      int src = grp*4 + ((g+s3)&3);
      int v = 0; long cnt = 0; bool to = false;
      do {
        v = __hip_atomic_load(&hsk1[src], __ATOMIC_ACQUIRE, __HIP_MEMORY_SCOPE_AGENT);
        if (++cnt > (1l<<20)){ to = true; break; }
      } while ((v & ~255) != tag);
      if (to || (v&15) != (xcc&15)) fast = 0;
      else if (ld_sc0_i(&probe[src]) != tag) fast = 0;   // functional same-L2 probe
    }
    __hip_atomic_store(&hsk2[grp*4+g], tag | fast, __ATOMIC_RELEASE, __HIP_MEMORY_SCOPE_AGENT);
    for (int s3=1; s3<4; s3++){
      int src = grp*4 + ((g+s3)&3);
      int v = 0; long cnt = 0;
      do {
        v = __hip_atomic_load(&hsk2[src], __ATOMIC_ACQUIRE, __HIP_MEMORY_SCOPE_AGENT);
        if (++cnt > (1l<<26)) break;
      } while ((v & ~255) != tag);
      fast &= (v & 1);
    }
    fast_sh = fast;
  }
  // ---- state load ----
  float cst = 0.f, hpv = 0.f;
  const int j2 = t&255, b2 = t>>8;     // update mapping (t<512)
  if (t < 512){
    int bg = bp*2 + b2;
    hpv = st_h[(d*64+bg)*256 + j2];
    cst = st_c[(d*64+bg)*256 + j2];
    hl2[(j2>>6)*132 + (j2&63)*2 + b2] = hpv;
  }
  __syncthreads();
  const bool fastp = (fast_sh != 0);
  const float* xgb = xg + (long)(c0&1)*xg_par_str;

  for (int sp=0; sp<Sc; sp++){
    const int stepg = c0*Sc + sp;
    const int par = stepg & 1;
    const int target = stepg + 1;
    // prefetch this step's xg (latency hides under gemv+sync)
    float x0=0,x1=0,x2=0,x3=0;
    if (t < 512){
      const float* xr = xgb + ((long)(d*Sc+sp)*64 + (bp*2+b2))*1024 + j2;
      x0 = xr[0]; x1 = xr[256]; x2 = xr[512]; x3 = xr[768];
    }
    f32x2 s = gemv64(w, &hl2[c*132]);
    s.x = qsum(s.x); s.y = qsum(s.y);
    if (c == 0){
      float* sb = send + ((long)(par*64+grp)*4 + g)*512 + j*2;
      if (fastp) *(f32x2*)sb = s;
      else {
        union { f32x2 f; unsigned long long u; } cv; cv.f = s;
        __hip_atomic_store((unsigned long long*)sb, cv.u, __ATOMIC_RELAXED, __HIP_MEMORY_SCOPE_AGENT);
      }
    }
    __syncthreads();                       // per-wave vmcnt drain: sends in L2
    // R5: flag store in WAVE 1 (t==64), pollers in WAVE 0 (t<3) — waves are
    // independently scheduled, so the store can never deadlock behind polls.
    if (t == 64){
      if (fastp) flags[grp*4+g] = target;
      else __hip_atomic_store(&flags[grp*4+g], target, __ATOMIC_RELEASE, __HIP_MEMORY_SCOPE_AGENT);
    }
    if (t < 3){
      int src = grp*4 + ((g+1+t)&3);
      long cnt = 0;
      if (fastp){ while (ld_sc0_i(&flags[src]) < target){ if (++cnt > (1l<<18)) break; } }
      else { while (__hip_atomic_load(&flags[src], __ATOMIC_ACQUIRE, __HIP_MEMORY_SCOPE_AGENT) < target){ if (++cnt > (1l<<18)) break; } }
    }
    __syncthreads();                       // all 4 gates visible
    if (t < 512){
      const float* rb = send + (long)(par*64+grp)*4*512 + j2*2 + b2;
      float g0,g1,g2,g3;
      if (fastp){
        ld4_sc0(rb, rb+512, rb+1024, rb+1536, g0,g1,g2,g3);
      } else {
        g0 = __hip_atomic_load((const float*)(rb),      __ATOMIC_RELAXED, __HIP_MEMORY_SCOPE_AGENT);
        g1 = __hip_atomic_load((const float*)(rb+512),  __ATOMIC_RELAXED, __HIP_MEMORY_SCOPE_AGENT);
        g2 = __hip_atomic_load((const float*)(rb+1024), __ATOMIC_RELAXED, __HIP_MEMORY_SCOPE_AGENT);
        g3 = __hip_atomic_load((const float*)(rb+1536), __ATOMIC_RELAXED, __HIP_MEMORY_SCOPE_AGENT);
      }
      float pi = g0 + x0, pf = g1 + x1, pg = g2 + x2, po = g3 + x3;
      float ii = 1.f/(1.f+expf(-pi)), ff = 1.f/(1.f+expf(-pf));
      float gv = tanhf(pg),           oo = 1.f/(1.f+expf(-po));
      float cn = ff*cst + ii*gv;
      float hn = oo*tanhf(cn);
      if (ml[b2*Sc+sp] != 0){ cst = cn; hpv = hn; }   // freeze on masked steps
      hl2[(j2>>6)*132 + (j2&63)*2 + b2] = hpv;
      if (g == 0){
        int sg = d ? (SLEN-1-stepg) : stepg;
        hs[((long)sg*64 + (bp*2+b2))*512 + d*256 + j2] = hpv;
      }
    }
    __syncthreads();                       // hl2 ready for next gemv
  }
  if (t < 512){
    int bg = bp*2 + b2;
    st_h[(d*64+bg)*256 + j2] = hpv;
    st_c[(d*64+bg)*256 + j2] = cst;
  }
}

__global__ __launch_bounds__(576) void feats_k(
    const float* __restrict__ hs, const float* __restrict__ wout,
    float* __restrict__ feats)
{
  __shared__ __align__(16) float hlds[64*512];
  __shared__ __align__(16) float wl[NTAG*512];
  const int s = blockIdx.x, t = threadIdx.x;
  for (int i = t; i < 64*512/4; i += 576)
    ((f32x4*)hlds)[i] = ((const f32x4*)(hs + (long)s*64*512))[i];
  for (int i = t; i < NTAG*512/4; i += 576)
    ((f32x4*)wl)[i] = ((const f32x4*)wout)[i];
  __syncthreads();
  int b = t / 9, tag = t - b*9;
  float acc = 0.f;
  const float* hb = hlds + b*512;
  const float* wb = wl + tag*512;
  for (int k=0; k<512; k+=4){
    f32x4 h4 = *(const f32x4*)(hb+k);
    f32x4 w4 = *(const f32x4*)(wb+k);
    acc += h4.x*w4.x + h4.y*w4.y + h4.z*w4.z + h4.w*w4.w;
  }
  feats[((long)s*64 + b)*9 + tag] = acc;
}

__global__ __launch_bounds__(64) void viterbi_k(
    const int* __restrict__ ids, const float* __restrict__ feats,
    const float* __restrict__ bout, const float* __restrict__ trans,
    int* __restrict__ outp)
{
  __shared__ float fl[SLEN*NTAG + 64];
  __shared__ unsigned char bps[SLEN*NTAG];
  __shared__ unsigned char mk[SLEN];
  const int b = blockIdx.x, lane = threadIdx.x;
  for (int i=lane; i<SLEN; i+=64) mk[i] = (ids[b*SLEN+i] != 0) ? 1 : 0;
  for (int i=lane; i<SLEN*NTAG; i+=64){
    int s = i/9; int t = i - s*9;
    fl[i] = feats[((long)s*64+b)*9 + t] + bout[t];
  }
  fl[SLEN*NTAG + lane] = 0.f;
  __syncthreads();

  float Tc[9], v[9], vown;
  #pragma unroll
  for (int i=0;i<9;i++) Tc[i] = (lane<9)? trans[i*9 + lane] : 0.f;
  #pragma unroll
  for (int i=0;i<9;i++) v[i] = (i==0)?0.f:NEGV;
  vown = (lane==0)?0.f:NEGV;

  for (int s=0;s<SLEN;s++){
    float best = v[0] + Tc[0]; int bi = 0;
    #pragma unroll
    for (int i=1;i<9;i++){
      float sc = v[i] + Tc[i];
      if (sc > best){ best = sc; bi = i; }   // first-max tie-break
    }
    float nv = best + fl[s*9 + lane];
    bool m = mk[s] != 0;
    if (m && lane<9) vown = nv;
    if (lane < 9) bps[s*9+lane] = (unsigned char)bi;
    #pragma unroll
    for (int i=0;i<9;i++) v[i] = __shfl(vown, i);
  }
  if (lane == 0){
    float best = v[0]; int tag = 0;
    #pragma unroll
    for (int i=1;i<9;i++) if (v[i] > best){ best=v[i]; tag=i; }
    outp[b*SLEN + SLEN-1] = tag;
    for (int t=SLEN-1; t>=1; t--){
      int pv = bps[t*9 + tag];
      if (!mk[t]) pv = 0;
      outp[b*SLEN + t-1] = pv;
      tag = pv;
    }
  }
}

extern "C" void kernel_launch(void* const* d_in, const int* in_sizes, int n_in,
                              void* d_out, int out_size, void* d_ws, size_t ws_size,
                              hipStream_t stream){
  (void)in_sizes; (void)n_in; (void)out_size;
  const int*   ids   = (const int*)  d_in[0];
  const float* embed = (const float*)d_in[2];
  const float* Wih_f = (const float*)d_in[3];
  const float* Whh_f = (const float*)d_in[4];
  const float* b_f   = (const float*)d_in[5];
  const float* Wih_r = (const float*)d_in[6];
  const float* Whh_r = (const float*)d_in[7];
  const float* b_r   = (const float*)d_in[8];
  const float* Wout  = (const float*)d_in[9];
  const float* bout  = (const float*)d_in[10];
  const float* trans = (const float*)d_in[11];

  float* fw = (float*)d_ws;
  size_t off = 0;
  float* wS    = fw + off; off += 1048576;     // 4 MB swizzled Wih/Whh
  float* send  = fw + off; off += 262144;      // 1 MB (2 parities)
  float* st_h  = fw + off; off += 32768;
  float* st_c  = fw + off; off += 32768;
  float* hs    = fw + off; off += 16777216;    // 64 MB [512][64][512]
  float* featb = fw + off; off += 294912;      // [512][64][9]
  int*   flags = (int*)(fw + off); off += 256;
  int*   hsk1  = (int*)(fw + off); off += 256;
  int*   hsk2  = (int*)(fw + off); off += 256;
  int*   probe = (int*)(fw + off); off += 256;
  float* xg    = fw + off;
  size_t fixedB = off*4;

  const int cands[7] = {512,256,128,64,32,16,8};
  int Sc = 8;
  for (int ci=0; ci<7; ci++){
    size_t need = fixedB + (size_t)cands[ci]*262144*4;  // xg = 2par*2d*Sc*64*1024 f32
    if (need <= ws_size){ Sc = cands[ci]; break; }
  }
  const long xg_par_str = (long)Sc*131072;
  const int C = SLEN / Sc;

  hipMemsetAsync(flags, 0, 4096, stream);              // flags+hsk1+hsk2+probe
  hipMemsetAsync(st_h, 0, 2*32768*4, stream);          // st_h + st_c contiguous
  prep_k<<<1024,256,0,stream>>>(Wih_f, Whh_f, Wih_r, Whh_r, wS);
  for (int c0=0; c0<C; c0++){
    xproj_k<<<256,1024,0,stream>>>(c0, Sc, ids, embed, wS, b_f, b_r, xg, xg_par_str);
    recur_k<<<256,1024,0,stream>>>(c0, Sc, ids, wS, xg, xg_par_str, hs, st_h, st_c,
                                   send, flags, hsk1, hsk2, probe);
  }
  feats_k<<<512,576,0,stream>>>(hs, Wout, featb);
  viterbi_k<<<64,64,0,stream>>>(ids, featb, bout, trans, (int*)d_out);
}

// Round 6
// 3807.082 us; speedup vs baseline: 2258.3773x; 2258.3773x over previous
//
#include <hip/hip_runtime.h>

// BiLSTM-CRF, f32-faithful.
// R6: (1) weights by-construction resident: 32 f32/thread in NAMED struct
// fields (SROA-safe; R3-R5's arrays + "+v" asm refs alloca'd -> scratch,
// VGPR_Count=60, 3.18GB spill writes) + 32 f32/thread in LDS (128KB).
// (2) sync = R3's proven pure agent-atomic flag protocol (the sc0 "fast
// path" of R4/R5 never delivered flag visibility: runtime scaled with poll
// bailout constants). Gate-split: 4 blocks/chain-pair, each owns one gate's
// rows (256x256), exchanges complete gates (2KB/block/step).

#define SLEN 512
#define NTAG 9
#define NEGV -10000.0f

typedef float f32x2 __attribute__((ext_vector_type(2)));
typedef float f32x4 __attribute__((ext_vector_type(4)));

__device__ __forceinline__ float qsum(float v){
  int t = __builtin_amdgcn_update_dpp(0, __float_as_int(v), 0xB1, 0xF, 0xF, false); // [1,0,3,2]
  v += __int_as_float(t);
  t = __builtin_amdgcn_update_dpp(0, __float_as_int(v), 0x4E, 0xF, 0xF, false);     // [2,3,0,1]
  return v + __int_as_float(t);
}

// dual-batch packed FMA: s.lo += W[k]*h[k,b0]; s.hi += W[k]*h[k,b1] (and k+1)
#define MAC2(S, WP, HV) { \
  f32x2 _h01{(HV).x,(HV).y}, _h23{(HV).z,(HV).w}; \
  asm("v_pk_fma_f32 %0, %1, %2, %0 op_sel:[0,0,0] op_sel_hi:[0,1,1]" : "+v"(S) : "v"(WP), "v"(_h01)); \
  asm("v_pk_fma_f32 %0, %1, %2, %0 op_sel:[1,0,0] op_sel_hi:[1,1,1]" : "+v"(S) : "v"(WP), "v"(_h23)); }

// 16 NAMED f32x2 pairs = 32 f32 of per-thread weights (k_local 0..31)
struct WReg { f32x2 a0,a1,a2,a3,a4,a5,a6,a7,a8,a9,a10,a11,a12,a13,a14,a15; };

__device__ __forceinline__ WReg load_wreg(const f32x4* __restrict__ wp, int t){
  WReg r; f32x4 v;
  v = wp[0*1024+t]; r.a0  = f32x2{v.x,v.y}; r.a1  = f32x2{v.z,v.w};
  v = wp[1*1024+t]; r.a2  = f32x2{v.x,v.y}; r.a3  = f32x2{v.z,v.w};
  v = wp[2*1024+t]; r.a4  = f32x2{v.x,v.y}; r.a5  = f32x2{v.z,v.w};
  v = wp[3*1024+t]; r.a6  = f32x2{v.x,v.y}; r.a7  = f32x2{v.z,v.w};
  v = wp[4*1024+t]; r.a8  = f32x2{v.x,v.y}; r.a9  = f32x2{v.z,v.w};
  v = wp[5*1024+t]; r.a10 = f32x2{v.x,v.y}; r.a11 = f32x2{v.z,v.w};
  v = wp[6*1024+t]; r.a12 = f32x2{v.x,v.y}; r.a13 = f32x2{v.z,v.w};
  v = wp[7*1024+t]; r.a14 = f32x2{v.x,v.y}; r.a15 = f32x2{v.z,v.w};
  return r;
}

// gemv over this thread's 64-k slice (quarter c), dual batch.
// hb = quarter base in LDS (interleaved (k,b) pairs). lw = LDS weight chunks
// (k_local 32..63). Returns {sum_b0, sum_b1} partial (quad-reduce after).
__device__ __forceinline__ f32x2 gemv_step(const WReg &w, const f32x4* lw, int t,
                                           const float* hb){
  f32x2 s{0.f,0.f};
  f32x4 h;
  h = *(const f32x4*)(hb+ 0); MAC2(s, w.a0,  h);
  h = *(const f32x4*)(hb+ 4); MAC2(s, w.a1,  h);
  h = *(const f32x4*)(hb+ 8); MAC2(s, w.a2,  h);
  h = *(const f32x4*)(hb+12); MAC2(s, w.a3,  h);
  h = *(const f32x4*)(hb+16); MAC2(s, w.a4,  h);
  h = *(const f32x4*)(hb+20); MAC2(s, w.a5,  h);
  h = *(const f32x4*)(hb+24); MAC2(s, w.a6,  h);
  h = *(const f32x4*)(hb+28); MAC2(s, w.a7,  h);
  h = *(const f32x4*)(hb+32); MAC2(s, w.a8,  h);
  h = *(const f32x4*)(hb+36); MAC2(s, w.a9,  h);
  h = *(const f32x4*)(hb+40); MAC2(s, w.a10, h);
  h = *(const f32x4*)(hb+44); MAC2(s, w.a11, h);
  h = *(const f32x4*)(hb+48); MAC2(s, w.a12, h);
  h = *(const f32x4*)(hb+52); MAC2(s, w.a13, h);
  h = *(const f32x4*)(hb+56); MAC2(s, w.a14, h);
  h = *(const f32x4*)(hb+60); MAC2(s, w.a15, h);
  #pragma unroll
  for (int q=0; q<8; q++){
    f32x4 wc = lw[q*1024 + t];
    f32x4 hA = *(const f32x4*)(hb + 64 + 8*q);
    f32x4 hB = *(const f32x4*)(hb + 68 + 8*q);
    f32x2 w1{wc.x,wc.y}; MAC2(s, w1, hA);
    f32x2 w2{wc.z,wc.w}; MAC2(s, w2, hB);
  }
  return s;
}

// wS[((((role*2+d)*4+g)*2+m)*8+q)*4096 + t*4 + e] =
//   W_role_d[g*256 + (t>>2)][(t&3)*64 + m*32 + q*4 + e]   (role0=Wih,1=Whh)
__global__ void prep_k(const float* __restrict__ wihf, const float* __restrict__ whhf,
                       const float* __restrict__ wihr, const float* __restrict__ whhr,
                       float* __restrict__ wS){
  for (int i = blockIdx.x*blockDim.x + threadIdx.x; i < (1<<20); i += gridDim.x*blockDim.x){
    int e=i&3, t=(i>>2)&1023, q=(i>>12)&7, m=(i>>15)&1, g=(i>>16)&3, d=(i>>18)&1, role=(i>>19)&1;
    int j = t>>2, c = t&3;
    int k = c*64 + m*32 + q*4 + e;
    const float* s = role ? (d? whhr : whhf) : (d? wihr : wihf);
    wS[i] = s[(g*256 + j)*256 + k];
  }
}

// xproj: block (d, g, bp) computes gate-g pre-activations (incl. bias) for
// batches {2bp, 2bp+1}, Sc steps of chunk c0. Double-buffered LDS x.
__global__ __launch_bounds__(1024, 4) void xproj_k(
    int c0, int Sc,
    const int* __restrict__ ids, const float* __restrict__ embed,
    const float* __restrict__ wS,
    const float* __restrict__ bias_f, const float* __restrict__ bias_r,
    float* __restrict__ xg, long xg_par_str)
{
  __shared__ f32x4 lw4[8192];                    // 128KB weight slice (k_local 32..63)
  __shared__ __align__(16) float xl2[2][544];
  __shared__ int ids_l[1024];
  const int t = threadIdx.x;
  const int bid = blockIdx.x;
  const int bp = bid & 31, g = (bid>>5)&3, d = bid>>7;
  const int j = t>>2, c = t&3;

  const f32x4* wp = (const f32x4*)(wS + ((long)((0*2+d)*4+g)*2)*32768);
  WReg w = load_wreg(wp, t);
  #pragma unroll
  for (int q=0; q<8; q++) lw4[q*1024+t] = wp[(8+q)*1024 + t];

  const float bb = (d ? bias_r : bias_f)[g*256 + j];
  for (int i=t; i<2*Sc; i+=1024){
    int b = (i>=Sc) ? 1 : 0, sp = i - b*Sc;
    int sg = d ? (SLEN-1-(c0*Sc+sp)) : (c0*Sc+sp);
    ids_l[i] = ids[(bp*2+b)*SLEN + sg];
  }
  __syncthreads();
  const int bl = t&1, kk = t>>1;                 // loader mapping (t<128)
  if (t < 128){
    f32x4 v = ((const f32x4*)embed)[(long)ids_l[bl*Sc]*64 + kk];
    #pragma unroll
    for (int ii=0; ii<4; ii++){
      int k = kk*4+ii;
      xl2[0][(k>>6)*132 + (k&63)*2 + bl] = v[ii];
    }
  }
  __syncthreads();
  float* xgb = xg + (long)(c0&1)*xg_par_str;
  for (int sp=0; sp<Sc; sp++){
    f32x4 pfv;
    const bool hpf = (sp+1 < Sc) && (t < 128);
    if (hpf) pfv = ((const f32x4*)embed)[(long)ids_l[bl*Sc + sp+1]*64 + kk];
    f32x2 s = gemv_step(w, lw4, t, &xl2[sp&1][c*132]);
    float s0 = qsum(s.x), s1 = qsum(s.y);
    if (c < 2){
      float val = (c ? s1 : s0) + bb;
      xgb[((long)(d*Sc+sp)*64 + (bp*2+c))*1024 + g*256 + j] = val;
    }
    if (hpf){
      #pragma unroll
      for (int ii=0; ii<4; ii++){
        int k = kk*4+ii;
        xl2[(sp+1)&1][(k>>6)*132 + (k&63)*2 + bl] = pfv[ii];
      }
    }
    __syncthreads();
  }
}

// recur: blockIdx bits [2:0]=grp_lo, [4:3]=g, [7:5]=grp_hi. Group = 4 gate
// blocks of one (d,bp) chain-pair. Pure agent-atomic sync (R3-proven).
__global__ __launch_bounds__(1024, 4) void recur_k(
    int c0, int Sc,
    const int* __restrict__ ids,
    const float* __restrict__ wS,
    const float* __restrict__ xg, long xg_par_str,
    float* __restrict__ hs,
    float* __restrict__ st_h, float* __restrict__ st_c,
    float* __restrict__ send, int* __restrict__ flags)
{
  __shared__ f32x4 lw4[8192];                    // 128KB weight slice
  __shared__ __align__(16) float hl2[544];
  __shared__ int ml[1024];
  const int t = threadIdx.x;
  const int bid = blockIdx.x;
  const int g = (bid>>3)&3;
  const int grp = (bid&7) | ((bid>>5)<<3);
  const int d = grp>>5, bp = grp&31;
  const int j = t>>2, c = t&3;

  const f32x4* wp = (const f32x4*)(wS + ((long)((1*2+d)*4+g)*2)*32768);
  WReg w = load_wreg(wp, t);
  #pragma unroll
  for (int q=0; q<8; q++) lw4[q*1024+t] = wp[(8+q)*1024 + t];

  for (int i=t; i<2*Sc; i+=1024){
    int b = (i>=Sc) ? 1 : 0, sp = i - b*Sc;
    int sg = d ? (SLEN-1-(c0*Sc+sp)) : (c0*Sc+sp);
    ml[i] = ids[(bp*2+b)*SLEN + sg];
  }
  float cst = 0.f, hpv = 0.f;
  const int j2 = t&255, b2 = t>>8;               // update mapping (t<512)
  if (t < 512){
    int bg = bp*2 + b2;
    hpv = st_h[(d*64+bg)*256 + j2];
    cst = st_c[(d*64+bg)*256 + j2];
    hl2[(j2>>6)*132 + (j2&63)*2 + b2] = hpv;
  }
  __syncthreads();
  const float* xgb = xg + (long)(c0&1)*xg_par_str;

  for (int sp=0; sp<Sc; sp++){
    const int stepg = c0*Sc + sp;
    const int par = stepg & 1;
    const int target = stepg + 1;
    float x0=0,x1=0,x2=0,x3=0;
    if (t < 512){
      const float* xr = xgb + ((long)(d*Sc+sp)*64 + (bp*2+b2))*1024 + j2;
      x0 = xr[0]; x1 = xr[256]; x2 = xr[512]; x3 = xr[768];
    }
    f32x2 s = gemv_step(w, lw4, t, &hl2[c*132]);
    float s0 = qsum(s.x), s1 = qsum(s.y);
    if (c == 0){
      union { float f[2]; unsigned long long u; } cv; cv.f[0]=s0; cv.f[1]=s1;
      __hip_atomic_store((unsigned long long*)(send + ((long)(par*64+grp)*4 + g)*512 + j*2),
                         cv.u, __ATOMIC_RELAXED, __HIP_MEMORY_SCOPE_AGENT);
    }
    __syncthreads();                             // vmcnt drained: sends visible
    if (t == 0)
      __hip_atomic_store(&flags[grp*4+g], target, __ATOMIC_RELEASE, __HIP_MEMORY_SCOPE_AGENT);
    if (t < 3){                                  // same-lane-stream: store precedes poll
      int src = grp*4 + ((g+1+t)&3);
      int cnt = 0;
      while (__hip_atomic_load(&flags[src], __ATOMIC_ACQUIRE, __HIP_MEMORY_SCOPE_AGENT) < target){
        if (++cnt > (1<<16)) break;
      }
    }
    __syncthreads();                             // all 4 gates visible
    if (t < 512){
      const float* rb = send + (long)(par*64+grp)*4*512 + j2*2 + b2;
      float g0 = __hip_atomic_load(rb,      __ATOMIC_RELAXED, __HIP_MEMORY_SCOPE_AGENT);
      float g1 = __hip_atomic_load(rb+512,  __ATOMIC_RELAXED, __HIP_MEMORY_SCOPE_AGENT);
      float g2 = __hip_atomic_load(rb+1024, __ATOMIC_RELAXED, __HIP_MEMORY_SCOPE_AGENT);
      float g3 = __hip_atomic_load(rb+1536, __ATOMIC_RELAXED, __HIP_MEMORY_SCOPE_AGENT);
      float pi = g0 + x0, pf = g1 + x1, pg = g2 + x2, po = g3 + x3;
      float ii = 1.f/(1.f+expf(-pi)), ff = 1.f/(1.f+expf(-pf));
      float gv = tanhf(pg),           oo = 1.f/(1.f+expf(-po));
      float cn = ff*cst + ii*gv;
      float hn = oo*tanhf(cn);
      if (ml[b2*Sc+sp] != 0){ cst = cn; hpv = hn; }   // freeze on masked steps
      hl2[(j2>>6)*132 + (j2&63)*2 + b2] = hpv;
      if (g == 0){
        int sg = d ? (SLEN-1-stepg) : stepg;
        hs[((long)sg*64 + (bp*2+b2))*512 + d*256 + j2] = hpv;
      }
    }
    __syncthreads();                             // hl2 ready for next gemv
  }
  if (t < 512){
    int bg = bp*2 + b2;
    st_h[(d*64+bg)*256 + j2] = hpv;
    st_c[(d*64+bg)*256 + j2] = cst;
  }
}

__global__ __launch_bounds__(576) void feats_k(
    const float* __restrict__ hs, const float* __restrict__ wout,
    float* __restrict__ feats)
{
  __shared__ __align__(16) float hlds[64*512];
  __shared__ __align__(16) float wl[NTAG*512];
  const int s = blockIdx.x, t = threadIdx.x;
  for (int i = t; i < 64*512/4; i += 576)
    ((f32x4*)hlds)[i] = ((const f32x4*)(hs + (long)s*64*512))[i];
  for (int i = t; i < NTAG*512/4; i += 576)
    ((f32x4*)wl)[i] = ((const f32x4*)wout)[i];
  __syncthreads();
  int b = t / 9, tag = t - b*9;
  float acc = 0.f;
  const float* hb = hlds + b*512;
  const float* wb = wl + tag*512;
  for (int k=0; k<512; k+=4){
    f32x4 h4 = *(const f32x4*)(hb+k);
    f32x4 w4 = *(const f32x4*)(wb+k);
    acc += h4.x*w4.x + h4.y*w4.y + h4.z*w4.z + h4.w*w4.w;
  }
  feats[((long)s*64 + b)*9 + tag] = acc;
}

__global__ __launch_bounds__(64) void viterbi_k(
    const int* __restrict__ ids, const float* __restrict__ feats,
    const float* __restrict__ bout, const float* __restrict__ trans,
    int* __restrict__ outp)
{
  __shared__ float fl[SLEN*NTAG + 64];
  __shared__ unsigned char bps[SLEN*NTAG];
  __shared__ unsigned char mk[SLEN];
  const int b = blockIdx.x, lane = threadIdx.x;
  for (int i=lane; i<SLEN; i+=64) mk[i] = (ids[b*SLEN+i] != 0) ? 1 : 0;
  for (int i=lane; i<SLEN*NTAG; i+=64){
    int s = i/9; int t = i - s*9;
    fl[i] = feats[((long)s*64+b)*9 + t] + bout[t];
  }
  fl[SLEN*NTAG + lane] = 0.f;
  __syncthreads();

  float Tc[9], v[9], vown;
  #pragma unroll
  for (int i=0;i<9;i++) Tc[i] = (lane<9)? trans[i*9 + lane] : 0.f;
  #pragma unroll
  for (int i=0;i<9;i++) v[i] = (i==0)?0.f:NEGV;
  vown = (lane==0)?0.f:NEGV;

  for (int s=0;s<SLEN;s++){
    float best = v[0] + Tc[0]; int bi = 0;
    #pragma unroll
    for (int i=1;i<9;i++){
      float sc = v[i] + Tc[i];
      if (sc > best){ best = sc; bi = i; }       // first-max tie-break
    }
    float nv = best + fl[s*9 + lane];
    bool m = mk[s] != 0;
    if (m && lane<9) vown = nv;
    if (lane < 9) bps[s*9+lane] = (unsigned char)bi;
    #pragma unroll
    for (int i=0;i<9;i++) v[i] = __shfl(vown, i);
  }
  if (lane == 0){
    float best = v[0]; int tag = 0;
    #pragma unroll
    for (int i=1;i<9;i++) if (v[i] > best){ best=v[i]; tag=i; }
    outp[b*SLEN + SLEN-1] = tag;
    for (int t=SLEN-1; t>=1; t--){
      int pv = bps[t*9 + tag];
      if (!mk[t]) pv = 0;
      outp[b*SLEN + t-1] = pv;
      tag = pv;
    }
  }
}

extern "C" void kernel_launch(void* const* d_in, const int* in_sizes, int n_in,
                              void* d_out, int out_size, void* d_ws, size_t ws_size,
                              hipStream_t stream){
  (void)in_sizes; (void)n_in; (void)out_size;
  const int*   ids   = (const int*)  d_in[0];
  const float* embed = (const float*)d_in[2];
  const float* Wih_f = (const float*)d_in[3];
  const float* Whh_f = (const float*)d_in[4];
  const float* b_f   = (const float*)d_in[5];
  const float* Wih_r = (const float*)d_in[6];
  const float* Whh_r = (const float*)d_in[7];
  const float* b_r   = (const float*)d_in[8];
  const float* Wout  = (const float*)d_in[9];
  const float* bout  = (const float*)d_in[10];
  const float* trans = (const float*)d_in[11];

  float* fw = (float*)d_ws;
  size_t off = 0;
  float* wS    = fw + off; off += 1048576;     // 4 MB swizzled Wih+Whh
  float* send  = fw + off; off += 262144;      // 1 MB (2 parities)
  float* st_h  = fw + off; off += 32768;
  float* st_c  = fw + off; off += 32768;
  float* hs    = fw + off; off += 16777216;    // 64 MB [512][64][512]
  float* featb = fw + off; off += 294912;      // [512][64][9]
  int*   flags = (int*)(fw + off); off += 256;
  float* xg    = fw + off;
  size_t fixedB = off*4;

  const int cands[7] = {512,256,128,64,32,16,8};
  int Sc = 8;
  for (int ci=0; ci<7; ci++){
    size_t need = fixedB + (size_t)cands[ci]*262144*4;  // xg = 2par*2d*Sc*64*1024 f32
    if (need <= ws_size){ Sc = cands[ci]; break; }
  }
  const long xg_par_str = (long)Sc*131072;
  const int C = SLEN / Sc;

  hipMemsetAsync(flags, 0, 1024, stream);
  hipMemsetAsync(st_h, 0, 2*32768*4, stream);          // st_h + st_c contiguous
  prep_k<<<1024,256,0,stream>>>(Wih_f, Whh_f, Wih_r, Whh_r, wS);
  for (int c0=0; c0<C; c0++){
    xproj_k<<<256,1024,0,stream>>>(c0, Sc, ids, embed, wS, b_f, b_r, xg, xg_par_str);
    recur_k<<<256,1024,0,stream>>>(c0, Sc, ids, wS, xg, xg_par_str, hs, st_h, st_c,
                                   send, flags);
  }
  feats_k<<<512,576,0,stream>>>(hs, Wout, featb);
  viterbi_k<<<64,64,0,stream>>>(ids, featb, bout, trans, (int*)d_out);
}